// Round 1
// baseline (555.063 us; speedup 1.0000x reference)
//
#include <hip/hip_runtime.h>

// Problem constants (B=4, Cin=64, Cout=128, H=W=128, 3x3, stride=1, pad=1, dil=1)
#define HW    16384
#define NB    4
#define CIN   64
#define COUT  128
#define KK    9
#define CKDIM 576      // CIN*KK
#define C2    128      // 2*CIN (om conv input channels)
#define TPX   32       // pixels per k_dcn block

// ---------------------------------------------------------------------------
// k_prep: transpose weights once per launch.
//  wt_om[(c*9+t)*32 + co] = w_om[co][c][t]   (co padded 27->32 for s_load runs)
//  wt[ck*128 + o]         = weight[o][ck]    (coalesced rows for phase-2 GEMM)
// ---------------------------------------------------------------------------
__global__ __launch_bounds__(256) void k_prep(const float* __restrict__ w_om,
                                              const float* __restrict__ weight,
                                              float* __restrict__ wt_om,
                                              float* __restrict__ wt) {
  int i = blockIdx.x * 256 + threadIdx.x;
  if (i < 1152 * 32) {
    int co = i & 31, ct = i >> 5;               // ct = c*9 + t
    wt_om[i] = (co < 27) ? w_om[co * 1152 + ct] : 0.f;
  }
  if (i < CKDIM * COUT) {
    int o = i & 127, ck = i >> 7;
    wt[i] = weight[o * CKDIM + ck];
  }
}

// ---------------------------------------------------------------------------
// k_om: 3x3 conv, Cin=128 (concat of input_feat & inter), Cout=27.
// One thread per (b, pixel); 27 fp32 accumulators; weight indices are
// wave-uniform -> scalar loads; inner loop is pure v_fma_f32.
// ---------------------------------------------------------------------------
__global__ __launch_bounds__(256) void k_om(const float* __restrict__ xin,
                                            const float* __restrict__ inter,
                                            const float* __restrict__ wt_om,
                                            const float* __restrict__ b_om,
                                            float* __restrict__ om) {
  int t = blockIdx.x * 256 + threadIdx.x;       // [0, 4*16384)
  int b = t >> 14;
  int hw = t & (HW - 1);
  int h = hw >> 7, w = hw & 127;

  float acc[27];
#pragma unroll
  for (int j = 0; j < 27; ++j) acc[j] = b_om[j];

  const float* xb = xin + (size_t)b * CIN * HW;
  const float* ib = inter + (size_t)b * CIN * HW;

  for (int c = 0; c < C2; ++c) {
    const float* src = (c < CIN) ? (xb + c * HW) : (ib + (c - CIN) * HW);
    float v[9];
#pragma unroll
    for (int t9 = 0; t9 < 9; ++t9) {
      int y = h + t9 / 3 - 1;
      int x = w + t9 % 3 - 1;
      v[t9] = ((unsigned)y < 128u && (unsigned)x < 128u) ? src[y * 128 + x] : 0.f;
    }
    const float* wr = wt_om + c * 9 * 32;
#pragma unroll
    for (int t9 = 0; t9 < 9; ++t9) {
#pragma unroll
      for (int co = 0; co < 27; ++co)
        acc[co] = fmaf(v[t9], wr[t9 * 32 + co], acc[co]);
    }
  }
  float* ob = om + (size_t)b * 27 * HW + hw;
#pragma unroll
  for (int co = 0; co < 27; ++co) ob[co * HW] = acc[co];
}

// ---------------------------------------------------------------------------
// k_dcn: modulated deformable conv.
// Block = 256 threads, tile = 32 pixels (one row segment), all 128 outputs.
// Phase 0: per (k,px) bilinear params (corner offsets, validity*mask-scaled
//          weights) into LDS.
// Phase 1: V[row][px] gathers into LDS (two 288-row chunks to keep LDS at
//          46 KB -> 3 blocks/CU).
// Phase 2: register-blocked 4o x 4px fp32 GEMM: per ck one coalesced float4
//          Wt load + one broadcast ds_read_b128 of V + 16 FMA.
// Epilogue: LDS transpose for coalesced dword stores.
// ---------------------------------------------------------------------------
__global__ __launch_bounds__(256) void k_dcn(const float* __restrict__ xin,
                                             const float* __restrict__ om,
                                             const float* __restrict__ wt,
                                             const float* __restrict__ bias,
                                             float* __restrict__ out) {
  __shared__ float  sV[288][TPX];   // 36864 B
  __shared__ float4 sW[KK][TPX];    //  4608 B  (corner weights * valid * mask)
  __shared__ int4   sO[KK][TPX];    //  4608 B  (clamped corner offsets)

  const int blk  = blockIdx.x;      // b * 512 + tile
  const int b    = blk >> 9;
  const int tile = blk & 511;
  const int hw0  = tile * TPX;      // 32 | 128 so a tile never crosses a row
  const int tid  = threadIdx.x;

  // ---- phase 0: bilinear params per (k, px) ----
  for (int item = tid; item < KK * TPX; item += 256) {
    int k  = item >> 5;
    int px = item & 31;
    int hw = hw0 + px;
    int h = hw >> 7, w = hw & 127;
    const float* ob = om + (size_t)b * 27 * HW + hw;
    float dy = ob[(2 * k) * HW];
    float dx = ob[(2 * k + 1) * HW];
    float mr = ob[(18 + k) * HW];
    float m  = 1.f / (1.f + __expf(-mr));
    float py  = (float)(k / 3 - 1 + h) + dy;
    float pxx = (float)(k % 3 - 1 + w) + dx;
    float y0f = floorf(py), x0f = floorf(pxx);
    float fy = py - y0f, fx = pxx - x0f;
    int y0 = (int)y0f, x0 = (int)x0f;
    int y1 = y0 + 1, x1 = x0 + 1;
    float vy0 = ((unsigned)y0 < 128u) ? 1.f : 0.f;
    float vy1 = ((unsigned)y1 < 128u) ? 1.f : 0.f;
    float vx0 = ((unsigned)x0 < 128u) ? 1.f : 0.f;
    float vx1 = ((unsigned)x1 < 128u) ? 1.f : 0.f;
    int yc0 = min(max(y0, 0), 127), yc1 = min(max(y1, 0), 127);
    int xc0 = min(max(x0, 0), 127), xc1 = min(max(x1, 0), 127);
    float gy0 = (1.f - fy) * m, gy1 = fy * m;
    sW[k][px] = make_float4(gy0 * (1.f - fx) * vy0 * vx0,
                            gy0 * fx         * vy0 * vx1,
                            gy1 * (1.f - fx) * vy1 * vx0,
                            gy1 * fx         * vy1 * vx1);
    sO[k][px] = make_int4(yc0 * 128 + xc0, yc0 * 128 + xc1,
                          yc1 * 128 + xc0, yc1 * 128 + xc1);
  }
  __syncthreads();

  const int px = tid & 31;          // phase-1 mapping
  const int g  = tid >> 5;
  const int og = tid & 31;          // phase-2 mapping
  const int pg = tid >> 5;
  const int o0 = og * 4, px0 = pg * 4;

  float acc[4][4];
#pragma unroll
  for (int i = 0; i < 4; ++i)
#pragma unroll
    for (int j = 0; j < 4; ++j) acc[i][j] = 0.f;

  const float* xb = xin + (size_t)b * CIN * HW;

  for (int cc = 0; cc < 2; ++cc) {
    const int ck0 = cc * 288;
    // ---- phase 1: gather V chunk into LDS ----
    for (int j = 0; j < 36; ++j) {
      int row = g + (j << 3);                 // [0, 288)
      int ck  = ck0 + row;
      int c   = ck / 9;
      int k   = ck - c * 9;
      float4 wv = sW[k][px];
      int4   ov = sO[k][px];
      const float* pl = xb + c * HW;
      float v = wv.x * pl[ov.x] + wv.y * pl[ov.y] +
                wv.z * pl[ov.z] + wv.w * pl[ov.w];
      sV[row][px] = v;
    }
    __syncthreads();

    // ---- phase 2: accumulate 288 ck's ----
#pragma unroll 4
    for (int ckr = 0; ckr < 288; ++ckr) {
      const float4 wv = *(const float4*)(wt + (size_t)(ck0 + ckr) * COUT + o0);
      const float4 vv = *(const float4*)(&sV[ckr][px0]);
      acc[0][0] = fmaf(wv.x, vv.x, acc[0][0]);
      acc[0][1] = fmaf(wv.x, vv.y, acc[0][1]);
      acc[0][2] = fmaf(wv.x, vv.z, acc[0][2]);
      acc[0][3] = fmaf(wv.x, vv.w, acc[0][3]);
      acc[1][0] = fmaf(wv.y, vv.x, acc[1][0]);
      acc[1][1] = fmaf(wv.y, vv.y, acc[1][1]);
      acc[1][2] = fmaf(wv.y, vv.z, acc[1][2]);
      acc[1][3] = fmaf(wv.y, vv.w, acc[1][3]);
      acc[2][0] = fmaf(wv.z, vv.x, acc[2][0]);
      acc[2][1] = fmaf(wv.z, vv.y, acc[2][1]);
      acc[2][2] = fmaf(wv.z, vv.z, acc[2][2]);
      acc[2][3] = fmaf(wv.z, vv.w, acc[2][3]);
      acc[3][0] = fmaf(wv.w, vv.x, acc[3][0]);
      acc[3][1] = fmaf(wv.w, vv.y, acc[3][1]);
      acc[3][2] = fmaf(wv.w, vv.z, acc[3][2]);
      acc[3][3] = fmaf(wv.w, vv.w, acc[3][3]);
    }
    __syncthreads();
  }

  // ---- epilogue: bias + LDS transpose for coalesced stores ----
  float* sOut = &sV[0][0];          // reuse: 128*33 = 4224 floats <= 9216
#pragma unroll
  for (int oi = 0; oi < 4; ++oi) {
    float bo = bias[o0 + oi];
    sOut[(o0 + oi) * 33 + px0 + 0] = acc[oi][0] + bo;
    sOut[(o0 + oi) * 33 + px0 + 1] = acc[oi][1] + bo;
    sOut[(o0 + oi) * 33 + px0 + 2] = acc[oi][2] + bo;
    sOut[(o0 + oi) * 33 + px0 + 3] = acc[oi][3] + bo;
  }
  __syncthreads();
  float* outb = out + (size_t)b * COUT * HW + hw0;
  for (int idx = tid; idx < COUT * TPX; idx += 256) {
    int o = idx >> 5, p = idx & 31;
    outb[(size_t)o * HW + p] = sOut[o * 33 + p];
  }
}

// ---------------------------------------------------------------------------
extern "C" void kernel_launch(void* const* d_in, const int* in_sizes, int n_in,
                              void* d_out, int out_size, void* d_ws, size_t ws_size,
                              hipStream_t stream) {
  const float* input_feat = (const float*)d_in[0];  // [4,64,128,128]
  const float* inter      = (const float*)d_in[1];  // [4,64,128,128]
  const float* weight     = (const float*)d_in[2];  // [128,64,3,3]
  const float* bias       = (const float*)d_in[3];  // [128]
  const float* w_om       = (const float*)d_in[4];  // [27,128,3,3]
  const float* b_om       = (const float*)d_in[5];  // [27]
  float* out = (float*)d_out;                       // [4,128,128,128]

  float* ws    = (float*)d_ws;
  float* wt_om = ws;                    // 36864 floats
  float* wt    = ws + 36864;            // 73728 floats
  float* om    = ws + 36864 + 73728;    // 4*27*16384 = 1769472 floats (~7.5 MB total)

  k_prep<<<288, 256, 0, stream>>>(w_om, weight, wt_om, wt);
  k_om<<<(NB * HW) / 256, 256, 0, stream>>>(input_feat, inter, wt_om, b_om, om);
  k_dcn<<<NB * (HW / TPX), 256, 0, stream>>>(input_feat, om, wt, bias, out);
}

// Round 2
// 261.049 us; speedup vs baseline: 2.1263x; 2.1263x over previous
//
#include <hip/hip_runtime.h>

// B=4, Cin=64, Cout=128, H=W=128, 3x3, stride=1, pad=1, dil=1
#define HW    16384
#define NB    4
#define CIN   64
#define COUT  128

typedef short  short8  __attribute__((ext_vector_type(8)));
typedef float  floatx4 __attribute__((ext_vector_type(4)));

// fp32 -> bf16 round-to-nearest-even
__device__ __forceinline__ short f2b(float f) {
  unsigned u = __float_as_uint(f);
  u += 0x7fff + ((u >> 16) & 1);
  return (short)(u >> 16);
}

// ---------------------------------------------------------------------------
// k_prep: bf16 weight repack into TAP-MAJOR K order (ck' = tap*C + c).
//  wtb  [o][k*64+c]  = bf16(weight[o][c][k])   o<128, K=576
//  wtbom[o][k*128+c] = bf16(w_om[o][c][k])     o<27 (padded to 32), K=1152
// ---------------------------------------------------------------------------
__global__ __launch_bounds__(256) void k_prep(const float* __restrict__ weight,
                                              const float* __restrict__ w_om,
                                              short* __restrict__ wtb,
                                              short* __restrict__ wtbom) {
  int i = blockIdx.x * 256 + threadIdx.x;
  if (i < 128 * 576) {
    int o = i / 576, r = i - o * 576;
    int k = r >> 6, c = r & 63;
    wtb[i] = f2b(weight[o * 576 + c * 9 + k]);
  }
  if (i < 32 * 1152) {
    int o = i / 1152, r = i - o * 1152;
    int k = r >> 7, c = r & 127;
    wtbom[i] = (o < 27) ? f2b(w_om[o * 1152 + c * 9 + k]) : (short)0;
  }
}

// ---------------------------------------------------------------------------
// k_om: 3x3 conv (Cin=128 concat, Cout=27) as im2col + bf16 MFMA.
// Block: 256 thr, 64-px row segment, M=32(o) x N=64(px), K=1152 in 9 tap-chunks
// of 128 channels. Wave w: Ntile px [w*16,w*16+16), both Mtiles.
// ---------------------------------------------------------------------------
#define KPAD_O 136            // 128 + 8 bf16 pad (row stride 272 B, 16B-aligned)
__global__ __launch_bounds__(256) void k_om(const float* __restrict__ xin,
                                            const float* __restrict__ inter,
                                            const short* __restrict__ wtbom,
                                            const float* __restrict__ b_om,
                                            float* __restrict__ om) {
  __shared__ __align__(16) short sV[64 * KPAD_O];   // 17408 B
  const int blk = blockIdx.x;
  const int b   = blk >> 8;
  const int hw0 = (blk & 255) * 64;
  const int tid = threadIdx.x;
  const int px1 = tid & 63;           // phase-1: one px per thread
  const int cg0 = tid >> 6;           // phase-1: channel-group base
  const int l15 = tid & 15, quad = (tid & 63) >> 4;
  const int wave = tid >> 6;
  const int hw = hw0 + px1;
  const int h = hw >> 7, w = hw & 127;
  const float* base0 = xin   + (size_t)b * CIN * HW;
  const float* base1 = inter + (size_t)b * CIN * HW;

  floatx4 acc0 = {0.f, 0.f, 0.f, 0.f};
  floatx4 acc1 = {0.f, 0.f, 0.f, 0.f};

  for (int ch = 0; ch < 9; ++ch) {
    // ---- phase 1: im2col chunk (tap ch, 128 channels) -> LDS bf16 ----
    int y = h + ch / 3 - 1;
    int x = w + ch % 3 - 1;
    bool valid = ((unsigned)y < 128u) && ((unsigned)x < 128u);
    int sofs = valid ? (y * 128 + x) : 0;
#pragma unroll
    for (int p = 0; p < 4; ++p) {
      int c0 = (cg0 + p * 4) * 8;
      const float* pl = (c0 < 64) ? (base0 + c0 * HW) : (base1 + (c0 - 64) * HW);
      short8 pk;
#pragma unroll
      for (int i = 0; i < 8; ++i) {
        float v = valid ? pl[i * HW + sofs] : 0.f;
        pk[i] = f2b(v);
      }
      *(short8*)(&sV[px1 * KPAD_O + c0]) = pk;
    }
    __syncthreads();

    // ---- phase 2: 4 K-steps x 2 MFMA ----
#pragma unroll
    for (int s = 0; s < 4; ++s) {
      int k0 = ch * 128 + s * 32;
      short8 a0 = *(const short8*)(&wtbom[l15 * 1152        + k0 + quad * 8]);
      short8 a1 = *(const short8*)(&wtbom[(16 + l15) * 1152 + k0 + quad * 8]);
      short8 bb = *(const short8*)(&sV[(wave * 16 + l15) * KPAD_O + s * 32 + quad * 8]);
      acc0 = __builtin_amdgcn_mfma_f32_16x16x32_bf16(a0, bb, acc0, 0, 0, 0);
      acc1 = __builtin_amdgcn_mfma_f32_16x16x32_bf16(a1, bb, acc1, 0, 0, 0);
    }
    __syncthreads();
  }

  // ---- epilogue: D[row=o][col=px], store o<27 ----
  float* ob = om + (size_t)b * 27 * HW + hw0 + wave * 16 + l15;
#pragma unroll
  for (int r = 0; r < 4; ++r) {
    int o = quad * 4 + r;
    if (o < 27) ob[o * HW] = acc0[r] + b_om[o];
    int o1 = 16 + quad * 4 + r;
    if (o1 < 27) ob[o1 * HW] = acc1[r] + b_om[o1];
  }
}

// ---------------------------------------------------------------------------
// k_dcn: modulated deformable conv, bf16 MFMA GEMM.
// Block: 256 thr, 32-px tile, M=128(o) x N=32(px), K=576 in 9 tap-chunks of 64
// channels. Wave w: o [w*32, w*32+32) (2 Mtiles) x 2 Ntiles.
// Phase 1: thread owns (px, tap): corner offsets/weights in regs, 8-channel
// gather groups, pack short8, one ds_write_b128.
// ---------------------------------------------------------------------------
#define KPAD_D 72             // 64 + 8 bf16 pad (row stride 144 B, 16B-aligned)
__global__ __launch_bounds__(256) void k_dcn(const float* __restrict__ xin,
                                             const float* __restrict__ om,
                                             const short* __restrict__ wtb,
                                             const float* __restrict__ bias,
                                             float* __restrict__ out) {
  __shared__ __align__(16) short sV[32 * KPAD_D];   //  4608 B
  __shared__ float4 sW[9][32];                      //  4608 B
  __shared__ int4   sO[9][32];                      //  4608 B
  const int blk = blockIdx.x;
  const int b   = blk >> 9;
  const int hw0 = (blk & 511) * 32;
  const int tid = threadIdx.x;

  // ---- phase 0: bilinear params per (tap, px) ----
  for (int item = tid; item < 9 * 32; item += 256) {
    int k  = item >> 5;
    int px = item & 31;
    int hw = hw0 + px;
    int h = hw >> 7, w = hw & 127;
    const float* ob = om + (size_t)b * 27 * HW + hw;
    float dy = ob[(2 * k) * HW];
    float dx = ob[(2 * k + 1) * HW];
    float mr = ob[(18 + k) * HW];
    float m  = 1.f / (1.f + __expf(-mr));
    float py  = (float)(k / 3 - 1 + h) + dy;
    float pxx = (float)(k % 3 - 1 + w) + dx;
    float y0f = floorf(py), x0f = floorf(pxx);
    float fy = py - y0f, fx = pxx - x0f;
    int y0 = (int)y0f, x0 = (int)x0f;
    int y1 = y0 + 1, x1 = x0 + 1;
    float vy0 = ((unsigned)y0 < 128u) ? 1.f : 0.f;
    float vy1 = ((unsigned)y1 < 128u) ? 1.f : 0.f;
    float vx0 = ((unsigned)x0 < 128u) ? 1.f : 0.f;
    float vx1 = ((unsigned)x1 < 128u) ? 1.f : 0.f;
    int yc0 = min(max(y0, 0), 127), yc1 = min(max(y1, 0), 127);
    int xc0 = min(max(x0, 0), 127), xc1 = min(max(x1, 0), 127);
    float gy0 = (1.f - fy) * m, gy1 = fy * m;
    sW[k][px] = make_float4(gy0 * (1.f - fx) * vy0 * vx0,
                            gy0 * fx         * vy0 * vx1,
                            gy1 * (1.f - fx) * vy1 * vx0,
                            gy1 * fx         * vy1 * vx1);
    sO[k][px] = make_int4(yc0 * 128 + xc0, yc0 * 128 + xc1,
                          yc1 * 128 + xc0, yc1 * 128 + xc1);
  }
  __syncthreads();

  const int px1 = tid & 31;           // phase-1 px
  const int cg  = tid >> 5;           // phase-1 channel group (8 channels)
  const int l15 = tid & 15, quad = (tid & 63) >> 4;
  const int wave = tid >> 6;
  const int ob0 = wave * 32;

  floatx4 acc00 = {0.f,0.f,0.f,0.f}, acc01 = {0.f,0.f,0.f,0.f};
  floatx4 acc10 = {0.f,0.f,0.f,0.f}, acc11 = {0.f,0.f,0.f,0.f};

  const float* xb = xin + (size_t)b * CIN * HW;

  for (int ch = 0; ch < 9; ++ch) {
    // ---- phase 1: gather chunk (tap ch, 64 channels) -> LDS bf16 ----
    float4 wv = sW[ch][px1];
    int4   ov = sO[ch][px1];
    const float* p0 = xb + cg * 8 * HW;
    short8 pk;
#pragma unroll
    for (int i = 0; i < 8; ++i) {
      const float* pc = p0 + i * HW;
      float v = wv.x * pc[ov.x] + wv.y * pc[ov.y] +
                wv.z * pc[ov.z] + wv.w * pc[ov.w];
      pk[i] = f2b(v);
    }
    *(short8*)(&sV[px1 * KPAD_D + cg * 8]) = pk;
    __syncthreads();

    // ---- phase 2: 2 K-steps x 4 MFMA ----
#pragma unroll
    for (int s = 0; s < 2; ++s) {
      int k0 = ch * 64 + s * 32;
      short8 a0 = *(const short8*)(&wtb[(ob0 + l15) * 576      + k0 + quad * 8]);
      short8 a1 = *(const short8*)(&wtb[(ob0 + 16 + l15) * 576 + k0 + quad * 8]);
      short8 bb0 = *(const short8*)(&sV[l15 * KPAD_D        + s * 32 + quad * 8]);
      short8 bb1 = *(const short8*)(&sV[(16 + l15) * KPAD_D + s * 32 + quad * 8]);
      acc00 = __builtin_amdgcn_mfma_f32_16x16x32_bf16(a0, bb0, acc00, 0, 0, 0);
      acc01 = __builtin_amdgcn_mfma_f32_16x16x32_bf16(a0, bb1, acc01, 0, 0, 0);
      acc10 = __builtin_amdgcn_mfma_f32_16x16x32_bf16(a1, bb0, acc10, 0, 0, 0);
      acc11 = __builtin_amdgcn_mfma_f32_16x16x32_bf16(a1, bb1, acc11, 0, 0, 0);
    }
    __syncthreads();
  }

  // ---- epilogue: D[row=o][col=px], coalesced 64B per quad ----
  float* outb = out + (size_t)b * COUT * HW + hw0;
#pragma unroll
  for (int r = 0; r < 4; ++r) {
    int o = ob0 + quad * 4 + r;
    float bo = bias[o];
    outb[(size_t)o * HW + l15]      = acc00[r] + bo;
    outb[(size_t)o * HW + 16 + l15] = acc01[r] + bo;
    int o1 = o + 16;
    float bo1 = bias[o1];
    outb[(size_t)o1 * HW + l15]      = acc10[r] + bo1;
    outb[(size_t)o1 * HW + 16 + l15] = acc11[r] + bo1;
  }
}

// ---------------------------------------------------------------------------
extern "C" void kernel_launch(void* const* d_in, const int* in_sizes, int n_in,
                              void* d_out, int out_size, void* d_ws, size_t ws_size,
                              hipStream_t stream) {
  const float* input_feat = (const float*)d_in[0];  // [4,64,128,128]
  const float* inter      = (const float*)d_in[1];  // [4,64,128,128]
  const float* weight     = (const float*)d_in[2];  // [128,64,3,3]
  const float* bias       = (const float*)d_in[3];  // [128]
  const float* w_om       = (const float*)d_in[4];  // [27,128,3,3]
  const float* b_om       = (const float*)d_in[5];  // [27]
  float* out = (float*)d_out;                       // [4,128,128,128]

  float* om    = (float*)d_ws;                           // 1769472 f32 (7.08 MB)
  short* wtb   = (short*)((char*)d_ws + 7077888);        // 73728 bf16
  short* wtbom = (short*)((char*)d_ws + 7225344);        // 36864 bf16

  k_prep<<<288, 256, 0, stream>>>(weight, w_om, wtb, wtbom);
  k_om<<<NB * (HW / 64), 256, 0, stream>>>(input_feat, inter, wtbom, b_om, om);
  k_dcn<<<NB * (HW / 32), 256, 0, stream>>>(input_feat, om, wtb, bias, out);
}